// Round 5
// baseline (84.634 us; speedup 1.0000x reference)
//
#include <hip/hip_runtime.h>
#include <hip/hip_bf16.h>

typedef __bf16 bf16x8 __attribute__((ext_vector_type(8)));
typedef __bf16 bf16x4 __attribute__((ext_vector_type(4)));
typedef float  f32x4  __attribute__((ext_vector_type(4)));

static constexpr int E    = 1965;   // J*D + J*3
static constexpr int KF   = 1920;   // J*D
static constexpr int NJ   = 15;
static constexpr int NCLS = 68;
static constexpr int NPAD = 80;     // 5 tiles of 16
static constexpr int NT   = 5;
static constexpr int NS   = 60;     // k-steps of 32

static constexpr int CH   = 6;      // chunks
static constexpr int CCOL = 320;    // fp32 cols per chunk
static constexpr int CST  = 10;     // k-steps per chunk
static constexpr int SEGS = 80;     // 4-float segments per chunk

// ws layout:
//   pnf: [NT][NS][64][8] __bf16  = 307200 B
//   pa : [NPAD][45] float        = 14400 B
static constexpr size_t PNF_BYTES = (size_t)NT * NS * 64 * 8 * 2;

// ---------------- kernel 1: normalize W -> bf16 fragments + angle extract ----
__global__ __launch_bounds__(256) void prep_kernel(const float* __restrict__ W,
                                                   __bf16* __restrict__ pnf,
                                                   float* __restrict__ pa) {
    const int n = blockIdx.x;      // 0..79
    const int t = threadIdx.x;     // 0..255
    float v[8];
    float ss = 0.f;
    if (n < NCLS && t < 240) {
        const float* src = W + (size_t)n * E + 8 * t;
        #pragma unroll
        for (int i = 0; i < 8; ++i) { v[i] = src[i]; ss += v[i] * v[i]; }
    } else {
        #pragma unroll
        for (int i = 0; i < 8; ++i) v[i] = 0.f;
    }
    #pragma unroll
    for (int off = 32; off >= 1; off >>= 1) ss += __shfl_xor(ss, off);
    __shared__ float rbuf[4];
    if ((t & 63) == 0) rbuf[t >> 6] = ss;
    __syncthreads();
    const float total = rbuf[0] + rbuf[1] + rbuf[2] + rbuf[3];
    const float rnorm = 1.f / fmaxf(sqrtf(total), 1e-12f);

    if (t < 240) {
        bf16x8 o;
        #pragma unroll
        for (int i = 0; i < 8; ++i) o[i] = (__bf16)(v[i] * rnorm);
        const int s = t >> 2, g = t & 3;
        const int lane = (n & 15) + 16 * g;
        const size_t off = (((size_t)(n >> 4) * NS + s) * 64 + lane) * 8;
        *(bf16x8*)(pnf + off) = o;
    }
    if (t < 45) {
        pa[n * 45 + t] = (n < NCLS) ? W[(size_t)n * E + KF + t] : 0.f;
    }
}

// ---------------- kernel 2: fused GEMM + norm + angle softmax ----------------
__global__ __launch_bounds__(320) void cos_kernel(const float* __restrict__ emb,
                                                  const __bf16* __restrict__ pnf,
                                                  const float* __restrict__ pa,
                                                  float* __restrict__ out) {
    // A chunk buffers: [seg][row][4 floats]; DMA dest contiguous in lane order.
    __shared__ f32x4  Abuf[2][SEGS][16];   // 40,960 B
    __shared__ __bf16 pal[NPAD][52];       //  8,320 B
    __shared__ float  xa[16][48];          //  3,072 B   -> total 52,352 B

    const int tid = threadIdx.x;
    const int m0  = blockIdx.x * 16;
    const int w   = tid >> 6;    // wave 0..4 (= N-tile)
    const int l   = tid & 63;
    const int lr  = l & 15;      // row within tile / B col
    const int lg  = l >> 4;      // k-group

    // ---- angle staging ----
    for (int idx = tid; idx < 16 * 45; idx += 320) {
        const int r = idx / 45, c = idx - r * 45;
        xa[r][c] = emb[(size_t)(m0 + r) * E + KF + c];
    }
    for (int idx = tid; idx < NPAD * 45; idx += 320) {
        const int n = idx / 45, c = idx - n * 45;
        pal[n][c] = (__bf16)pa[idx];
    }
    asm volatile("s_waitcnt lgkmcnt(0)" ::: "memory");   // angle ds_writes visible at next barrier

    // ---- register-free A staging: global_load_lds, 4 calls/chunk/wave ----
    // lane -> (row = l&15, seg = 16w + 4i + (l>>4)); dest = lane*16 contiguous
    const float* gbase = emb + (size_t)(m0 + lr) * E + (16 * w + lg) * 4;
    #define ISSUE_CHUNK(c)                                                              \
        {                                                                               \
            const float* g_ = gbase + (c) * CCOL;                                       \
            _Pragma("unroll")                                                           \
            for (int i_ = 0; i_ < 4; ++i_)                                              \
                __builtin_amdgcn_global_load_lds(                                       \
                    (const __attribute__((address_space(1))) void*)(g_ + i_ * 16),      \
                    (__attribute__((address_space(3))) void*)&Abuf[(c) & 1][16 * w + 4 * i_][0], \
                    16, 0, 0);                                                          \
        }

    ISSUE_CHUNK(0);

    const bf16x8* bp = (const bf16x8*)pnf + (size_t)w * NS * 64 + l;

    f32x4 acc[NJ];
    #pragma unroll
    for (int j = 0; j < NJ; ++j) acc[j] = f32x4{0.f, 0.f, 0.f, 0.f};
    float ssq = 0.f;

    #pragma unroll
    for (int c = 0; c < CH; ++c) {
        __builtin_amdgcn_s_barrier();          // prior readers of buf[(c+1)&1] done
        if (c + 1 < CH) {
            ISSUE_CHUNK(c + 1);
            asm volatile("s_waitcnt vmcnt(4)" ::: "memory");   // chunk c arrived, c+1 in flight
        } else {
            asm volatile("s_waitcnt vmcnt(0)" ::: "memory");
        }
        __builtin_amdgcn_s_barrier();          // all waves' chunk-c DMA arrived

        bf16x8 bfr[CST];
        #pragma unroll
        for (int s = 0; s < CST; ++s) bfr[s] = bp[(c * CST + s) * 64];

        #pragma unroll
        for (int s = 0; s < CST; ++s) {
            const f32x4 alo = Abuf[c & 1][8 * s + 2 * lg][lr];
            const f32x4 ahi = Abuf[c & 1][8 * s + 2 * lg + 1][lr];
            bf16x8 af;
            #pragma unroll
            for (int q = 0; q < 4; ++q) {
                ssq += alo[q] * alo[q];
                ssq += ahi[q] * ahi[q];
                af[q]     = (__bf16)alo[q];
                af[4 + q] = (__bf16)ahi[q];
            }
            acc[(c * CST + s) >> 2] =
                __builtin_amdgcn_mfma_f32_16x16x32_bf16(af, bfr[s], acc[(c * CST + s) >> 2], 0, 0, 0);
        }
    }
    #undef ISSUE_CHUNK

    // ---- row norms: every wave computed identical partials; pure shfl reduce ----
    ssq += __shfl_xor(ssq, 16);
    ssq += __shfl_xor(ssq, 32);               // full row-lr sum in every lane

    const int r0  = lg * 4;       // C/D: row = (lane>>4)*4 + reg, col = lane&15
    const int col = w * 16 + lr;

    float rn[4];
    #pragma unroll
    for (int r = 0; r < 4; ++r)
        rn[r] = 240.f / fmaxf(sqrtf(__shfl(ssq, r0 + r)), 1e-12f);   // 16*15/norm

    // ---- angle softmax epilogue ----
    float pr[45];
    #pragma unroll
    for (int q = 0; q < 12; ++q) {
        const bf16x4 pv = *(const bf16x4*)&pal[col][4 * q];
        #pragma unroll
        for (int e = 0; e < 4; ++e)
            if (4 * q + e < 45) pr[4 * q + e] = (float)pv[e];
    }

    float num[4] = {0.f, 0.f, 0.f, 0.f};
    float den[4] = {0.f, 0.f, 0.f, 0.f};
    #pragma unroll
    for (int r = 0; r < 4; ++r) {
        f32x4 xr[12];
        #pragma unroll
        for (int q = 0; q < 12; ++q)
            xr[q] = *(const f32x4*)&xa[r0 + r][4 * q];
        #pragma unroll
        for (int j = 0; j < NJ; ++j) {
            const float d0 = xr[(3 * j + 0) >> 2][(3 * j + 0) & 3] - pr[3 * j + 0];
            const float d1 = xr[(3 * j + 1) >> 2][(3 * j + 1) & 3] - pr[3 * j + 1];
            const float d2 = xr[(3 * j + 2) >> 2][(3 * j + 2) & 3] - pr[3 * j + 2];
            const float dist = sqrtf(d0 * d0 + d1 * d1 + d2 * d2);
            const float e = __expf(dist * 0.005f);   // exponents in [0, ~0.05]
            den[r] += e;
            num[r] += e * acc[j][r];
        }
    }

    if (col < NCLS) {
        #pragma unroll
        for (int r = 0; r < 4; ++r)
            out[(size_t)(m0 + r0 + r) * NCLS + col] = rn[r] * num[r] / den[r];
    }
}

extern "C" void kernel_launch(void* const* d_in, const int* in_sizes, int n_in,
                              void* d_out, int out_size, void* d_ws, size_t ws_size,
                              hipStream_t stream) {
    const float* emb = (const float*)d_in[0];
    const float* W   = (const float*)d_in[1];
    float* out = (float*)d_out;
    __bf16* pnf = (__bf16*)d_ws;
    float*  pa  = (float*)((char*)d_ws + PNF_BYTES);
    const int B = in_sizes[0] / E;           // 16384

    prep_kernel<<<NPAD, 256, 0, stream>>>(W, pnf, pa);
    cos_kernel<<<B / 16, 320, 0, stream>>>(emb, pnf, pa, out);
}